// Round 18
// baseline (576.349 us; speedup 1.0000x reference)
//
#include <hip/hip_runtime.h>

// WindowAttention fused, MI355X gfx950 — R17: occupancy x2 at constant regs.
// R16's bf16 xs (17.4KB) + bf16 mask (8.3KB) -> LDS 25.7KB -> 6 blocks/CU via
// __launch_bounds__(256,6); natural VGPR use (84) fits the cap (512/6=85).
// B=4096 windows, N=49 (pad 64), C=128, H=4 heads, d=32. wave w = head w.

typedef short bf16x4 __attribute__((ext_vector_type(4)));
typedef short bf16x8 __attribute__((ext_vector_type(8)));
typedef float f32x4 __attribute__((ext_vector_type(4)));
typedef unsigned int u32x4 __attribute__((ext_vector_type(4)));

#define MFMA_K32(a, b, c) __builtin_amdgcn_mfma_f32_16x16x32_bf16((a), (b), (c), 0, 0, 0)
#define MFMA_K16(a, b, c) __builtin_amdgcn_mfma_f32_16x16x16bf16_1k((a), (b), (c), 0, 0, 0)

// pack two fp32 -> two bf16 (round-half-up) in one u32 (R1-verified)
__device__ __forceinline__ unsigned pk2(float lo, float hi) {
  return __builtin_amdgcn_perm(__float_as_uint(hi) + 0x8000u,
                               __float_as_uint(lo) + 0x8000u, 0x07060302u);
}
__device__ __forceinline__ unsigned short bf1(float v) {
  return (unsigned short)((__float_as_uint(v) + 0x8000u) >> 16);
}
__device__ __forceinline__ float b2f(unsigned short u) {
  return __uint_as_float(((unsigned)u) << 16);
}
__device__ __forceinline__ bf16x4 pack4(float a, float b, float c, float d) {
  union { unsigned u[2]; bf16x4 h; } r;
  r.u[0] = pk2(a, b); r.u[1] = pk2(c, d);
  return r.h;
}

// ---- workspace layout (bytes) ----
#define OFF_QKVT  0u        // bf16 [384][128] W^T (col-major W), q-scale folded
#define OFF_PROJT 98304u    // bf16 [128][128] W^T
#define OFF_BIAST 131072u   // f32  [4][16 k4][64 q][4 ki]  vectorized rel-pos bias
#define OFF_BSC   196608u   // f32  [384] qkv_b (q part scaled)

__global__ void prep_kernel(const float* __restrict__ qkv_w,
                            const float* __restrict__ qkv_b,
                            const float* __restrict__ proj_w,
                            const float* __restrict__ bias_table,
                            const int*   __restrict__ rel_index,
                            char* __restrict__ ws) {
  const float scale = 0.17677669529663687f;  // 32^-0.5
  int idx = blockIdx.x * 256 + threadIdx.x;
  if (idx < 49152) {
    int n = idx >> 7, k = idx & 127;
    float v = qkv_w[k * 384 + n];
    if (n < 128) v *= scale;
    ((unsigned short*)(ws + OFF_QKVT))[idx] = bf1(v);
  } else if (idx < 65536) {
    int j = idx - 49152;
    int n = j >> 7, k = j & 127;
    ((unsigned short*)(ws + OFF_PROJT))[j] = bf1(proj_w[k * 128 + n]);
  } else if (idx < 75140) {                    // biasP[h][key>>2][q][key&3]
    int j = idx - 65536;
    int h = j / 2401, rem = j % 2401;
    int key = rem / 49, q = rem - key * 49;
    ((float*)(ws + OFF_BIAST))[h * 4096 + (key >> 2) * 256 + q * 4 + (key & 3)]
        = bias_table[rel_index[q * 49 + key] * 4 + h];
  } else if (idx < 75524) {
    int j = idx - 75140;
    float v = qkv_b[j];
    if (j < 128) v *= scale;
    ((float*)(ws + OFF_BSC))[j] = v;
  }
}

// LDS: [0,17408)       xs bf16 [64 tok][272B row] (256B data + 16B pad;
//                      stride 272 = 68 words ≡ 4 mod 32 -> ~2-way b128 reads).
//                      Rows 49..63 zeroed. First 16KB reused as `mid` bf16
//                      [64][256B] (byte = tok*256 + (2d ^ ((tok&15)<<4))).
//      [17408,25728)   mask bf16 [16 k4][520B]: byte = k4*520 + q*8 + ki*2
//                      (stride 520 = 130 words ≡ 2 mod 32; OOB slots garbage —
//                       discarded by the bounds select)
#define XSTR 272u
#define MSK  17408u

__global__ __launch_bounds__(256, 6)   // R17: 6 blocks/CU; natural 84 regs <= 512/6
void win_attn_kernel(const float* __restrict__ x,
                     const float* __restrict__ mask,
                     const float* __restrict__ proj_b,
                     const char*  __restrict__ ws,
                     float* __restrict__ out) {
  __shared__ __align__(16) char smem[25728];
  const int b    = blockIdx.x;
  const int tid  = threadIdx.x;
  const int w    = tid >> 6;        // wave id == head id
  const int lane = tid & 63;
  const int l16  = lane & 15;
  const int lg   = lane >> 4;

  const unsigned short* qkvT  = (const unsigned short*)(ws + OFF_QKVT);
  const unsigned short* projT = (const unsigned short*)(ws + OFF_PROJT);
  const float* bp  = (const float*)(ws + OFF_BIAST) + w * 4096;  // [k4][q][ki]
  const float* bsc = (const float*)(ws + OFF_BSC);

  // ============ stage x (bf16, pack-once) + mask (bf16, stride-520) -> LDS ============
  {
    const float* xb = x + (size_t)b * 6272;
#pragma unroll
    for (int it = 0; it < 4; ++it) {
      int idx = tid + it * 256;                // 1024 chunks of 8 bf16 (16B)
      int tok = idx >> 4, c8 = idx & 15;
      unsigned off = (unsigned)tok * XSTR + (unsigned)c8 * 16u;
      if (tok < 49) {
        const float* p = xb + tok * 128 + c8 * 8;
        float4 v0 = *(const float4*)p;
        float4 v1 = *(const float4*)(p + 4);
        *(uint4*)(smem + off) = make_uint4(pk2(v0.x, v0.y), pk2(v0.z, v0.w),
                                           pk2(v1.x, v1.y), pk2(v1.z, v1.w));
      } else {
        *(uint4*)(smem + off) = make_uint4(0u, 0u, 0u, 0u);
      }
    }
    const float* mb = mask + (size_t)b * 2401;
#pragma unroll
    for (int it = 0; it < 10; ++it) {
      int i = tid + it * 256;
      if (i < 2401) {
        int q = i / 49, key = i - q * 49;
        unsigned off = MSK + (unsigned)(key >> 2) * 520u +
                       (unsigned)q * 8u + ((unsigned)key & 3u) * 2u;
        *(unsigned short*)(smem + off) = bf1(mb[i]);
      }
    }
  }
  __syncthreads();

  // x fragment from LDS: single b128 (lane = token l16, 8 consecutive k bf16)
  auto xfrag = [&](int tt, int ks) -> bf16x8 {
    int tok = 16 * tt + l16;
    unsigned off = (unsigned)tok * XSTR + (unsigned)(64 * ks + 16 * lg);
    return *(const bf16x8*)(smem + off);
  };

  // ============ GEMM1 pass A: Q^T,K^T tiles = mfma(W^T-frag, x-frag) ============
  f32x4 qt_acc[2][4], kt_acc[2][4];
#pragma unroll
  for (int dt = 0; dt < 2; ++dt) {
    f32x4 qb, kb;
#pragma unroll
    for (int i = 0; i < 4; ++i) {
      qb[i] = bsc[32 * w + 16 * dt + 4 * lg + i];
      kb[i] = bsc[128 + 32 * w + 16 * dt + 4 * lg + i];
    }
#pragma unroll
    for (int tt = 0; tt < 4; ++tt) { qt_acc[dt][tt] = qb; kt_acc[dt][tt] = kb; }
  }
#pragma unroll
  for (int ks = 0; ks < 4; ++ks) {
    bf16x8 xf[4];
#pragma unroll
    for (int tt = 0; tt < 4; ++tt) xf[tt] = xfrag(tt, ks);
#pragma unroll
    for (int dt = 0; dt < 2; ++dt) {
      bf16x8 wq = *(const bf16x8*)(qkvT + (size_t)(32 * w + 16 * dt + l16) * 128 + 32 * ks + 8 * lg);
      bf16x8 wk = *(const bf16x8*)(qkvT + (size_t)(128 + 32 * w + 16 * dt + l16) * 128 + 32 * ks + 8 * lg);
#pragma unroll
      for (int tt = 0; tt < 4; ++tt) {
        qt_acc[dt][tt] = MFMA_K32(wq, xf[tt], qt_acc[dt][tt]);
        kt_acc[dt][tt] = MFMA_K32(wk, xf[tt], kt_acc[dt][tt]);
      }
    }
  }
  bf16x4 qf[4][2], kf[4][2];
#pragma unroll
  for (int tt = 0; tt < 4; ++tt)
#pragma unroll
    for (int dt = 0; dt < 2; ++dt) {
      qf[tt][dt] = pack4(qt_acc[dt][tt][0], qt_acc[dt][tt][1], qt_acc[dt][tt][2], qt_acc[dt][tt][3]);
      kf[tt][dt] = pack4(kt_acc[dt][tt][0], kt_acc[dt][tt][1], kt_acc[dt][tt][2], kt_acc[dt][tt][3]);
    }

  // ============ GEMM1 pass B: V tiles = mfma(x-frag, Wv^T-frag) ============
  f32x4 v_acc[4][2];
  {
    float vb0 = bsc[256 + 32 * w + l16];
    float vb1 = bsc[256 + 32 * w + 16 + l16];
#pragma unroll
    for (int tt = 0; tt < 4; ++tt) {
      v_acc[tt][0] = (f32x4){vb0, vb0, vb0, vb0};
      v_acc[tt][1] = (f32x4){vb1, vb1, vb1, vb1};
    }
  }
#pragma unroll
  for (int ks = 0; ks < 4; ++ks) {
    bf16x8 xf[4];
#pragma unroll
    for (int tt = 0; tt < 4; ++tt) xf[tt] = xfrag(tt, ks);   // LDS re-read, cheap
#pragma unroll
    for (int dt = 0; dt < 2; ++dt) {
      bf16x8 wv = *(const bf16x8*)(qkvT + (size_t)(256 + 32 * w + 16 * dt + l16) * 128 + 32 * ks + 8 * lg);
#pragma unroll
      for (int tt = 0; tt < 4; ++tt) v_acc[tt][dt] = MFMA_K32(xf[tt], wv, v_acc[tt][dt]);
    }
  }
  bf16x4 vf[2][4];
#pragma unroll
  for (int dt = 0; dt < 2; ++dt)
#pragma unroll
    for (int tt = 0; tt < 4; ++tt)
      vf[dt][tt] = pack4(v_acc[tt][dt][0], v_acc[tt][dt][1], v_acc[tt][dt][2], v_acc[tt][dt][3]);

  __syncthreads();   // all waves done reading xs; first 16KB becomes `mid`

  // ============ QK^T (K=16): S^T[key][q] tiles, lane = q, regs = key ============
  f32x4 s_acc[4][4];  // [kt][qt]
#pragma unroll
  for (int kt = 0; kt < 4; ++kt)
#pragma unroll
    for (int qt = 0; qt < 4; ++qt) s_acc[kt][qt] = (f32x4){0.f, 0.f, 0.f, 0.f};
#pragma unroll
  for (int kt = 0; kt < 4; ++kt)
#pragma unroll
    for (int qt = 0; qt < 4; ++qt) {
      s_acc[kt][qt] = MFMA_K16(kf[kt][0], qf[qt][0], s_acc[kt][qt]);
      s_acc[kt][qt] = MFMA_K16(kf[kt][1], qf[qt][1], s_acc[kt][qt]);
    }

  // ====== bias (float4, coalesced) + mask (LDS bf16x4) + no-max softmax ======
  float rs_[4];
#pragma unroll
  for (int qt = 0; qt < 4; ++qt) {
    int q = 16 * qt + l16;
    bool qok = q < 49;
    float sum = 0.f;
#pragma unroll
    for (int kt = 0; kt < 4; ++kt) {
      int k4 = 4 * kt + lg;
      float4 bv = *(const float4*)(bp + k4 * 256 + q * 4);
      ushort4 mu = *(const ushort4*)(smem + MSK + (unsigned)k4 * 520u + (unsigned)q * 8u);
      float ba[4] = {bv.x + b2f(mu.x), bv.y + b2f(mu.y),
                     bv.z + b2f(mu.z), bv.w + b2f(mu.w)};
#pragma unroll
      for (int i = 0; i < 4; ++i) {
        int key = 16 * kt + 4 * lg + i;
        float v = s_acc[kt][qt][i];
        v = (qok && key < 49) ? (v + ba[i]) : -30000.0f;
        float e = __expf(v - 8.0f);
        s_acc[kt][qt][i] = e;
        sum += e;
      }
    }
    sum += __shfl_xor(sum, 16);
    sum += __shfl_xor(sum, 32);
    rs_[qt] = 1.0f / (sum + 1e-30f);   // padded rows: sum==0 -> rs finite
  }

  // ============ P frags in-register; PV (K=16): O^T[d][q], lane = q ============
  bf16x4 pf[4][4];  // [qt][kt]
#pragma unroll
  for (int qt = 0; qt < 4; ++qt)
#pragma unroll
    for (int kt = 0; kt < 4; ++kt)
      pf[qt][kt] = pack4(s_acc[kt][qt][0], s_acc[kt][qt][1], s_acc[kt][qt][2], s_acc[kt][qt][3]);

  f32x4 o_acc[2][4];  // [dt][qt]: lane = q, regs = d = 4lg+i
#pragma unroll
  for (int dt = 0; dt < 2; ++dt)
#pragma unroll
    for (int qt = 0; qt < 4; ++qt) o_acc[dt][qt] = (f32x4){0.f, 0.f, 0.f, 0.f};
#pragma unroll
  for (int kt = 0; kt < 4; ++kt)
#pragma unroll
    for (int dt = 0; dt < 2; ++dt)
#pragma unroll
      for (int qt = 0; qt < 4; ++qt)
        o_acc[dt][qt] = MFMA_K16(vf[dt][kt], pf[qt][kt], o_acc[dt][qt]);

  // ============ normalize + write mid[q][32w+16dt+4lg..+3] (uint2) ============
#pragma unroll
  for (int qt = 0; qt < 4; ++qt) {
    int q = 16 * qt + l16;
    float r = rs_[qt];
    unsigned rowb = (unsigned)q * 256u, sw = ((unsigned)q & 15u) << 4;
#pragma unroll
    for (int dt = 0; dt < 2; ++dt) {
      unsigned u0 = pk2(o_acc[dt][qt][0] * r, o_acc[dt][qt][1] * r);
      unsigned u1 = pk2(o_acc[dt][qt][2] * r, o_acc[dt][qt][3] * r);
      unsigned L = (unsigned)(64 * w + 32 * dt + 8 * lg);
      *(uint2*)(smem + rowb + (L ^ sw)) = make_uint2(u0, u1);
    }
  }
  __syncthreads();

  // ============ GEMM2 (K=32): out = mid @ projW + b; wave w: cols 32w..32w+31 ============
  f32x4 c2[2][4];
#pragma unroll
  for (int nt = 0; nt < 2; ++nt) {
    float pbv = proj_b[32 * w + 16 * nt + l16];
#pragma unroll
    for (int mt = 0; mt < 4; ++mt) c2[nt][mt] = (f32x4){pbv, pbv, pbv, pbv};
  }
#pragma unroll
  for (int ks = 0; ks < 4; ++ks) {
    bf16x8 a2[4];
#pragma unroll
    for (int mt = 0; mt < 4; ++mt) {
      int tok = 16 * mt + l16;
      unsigned byte = (unsigned)tok * 256u +
                      (((unsigned)(64 * ks + 16 * lg)) ^ (((unsigned)tok & 15u) << 4));
      a2[mt] = *(const bf16x8*)(smem + byte);
    }
#pragma unroll
    for (int nt = 0; nt < 2; ++nt) {
      bf16x8 b2 = *(const bf16x8*)(projT + (size_t)(32 * w + 16 * nt + l16) * 128 + 32 * ks + 8 * lg);
#pragma unroll
      for (int mt = 0; mt < 4; ++mt) c2[nt][mt] = MFMA_K32(a2[mt], b2, c2[nt][mt]);
    }
  }
  float* ob = out + (size_t)b * 6272;
#pragma unroll
  for (int mt = 0; mt < 4; ++mt)
#pragma unroll
    for (int nt = 0; nt < 2; ++nt)
#pragma unroll
      for (int i = 0; i < 4; ++i) {
        int r = 16 * mt + 4 * lg + i;
        if (r < 49) ob[r * 128 + 32 * w + 16 * nt + l16] = c2[nt][mt][i];
      }
}

extern "C" void kernel_launch(void* const* d_in, const int* in_sizes, int n_in,
                              void* d_out, int out_size, void* d_ws, size_t ws_size,
                              hipStream_t stream) {
  const float* x          = (const float*)d_in[0];
  const float* mask       = (const float*)d_in[1];
  const float* qkv_w      = (const float*)d_in[2];
  const float* qkv_b      = (const float*)d_in[3];
  const float* proj_w     = (const float*)d_in[4];
  const float* proj_b     = (const float*)d_in[5];
  const float* bias_table = (const float*)d_in[6];
  const int*   rel_index  = (const int*)d_in[7];
  char* ws = (char*)d_ws;

  prep_kernel<<<296, 256, 0, stream>>>(qkv_w, qkv_b, proj_w, bias_table, rel_index, ws);
  win_attn_kernel<<<4096, 256, 0, stream>>>(x, mask, proj_b, ws, (float*)d_out);
}

// Round 19
// 123.052 us; speedup vs baseline: 4.6838x; 4.6838x over previous
//
#include <hip/hip_runtime.h>

// WindowAttention fused, MI355X gfx950 — R18: R14 (116us verified) + ONE
// change: operand-swapped GEMM2 (C holds out^T) -> epilogue is 8 predicated
// float4 stores instead of 32 scalar stores + 32 bounds checks.
// B=4096 windows, N=49 (pad 64), C=128, H=4 heads, d=32. wave w = head w.

typedef short bf16x4 __attribute__((ext_vector_type(4)));
typedef short bf16x8 __attribute__((ext_vector_type(8)));
typedef float f32x4 __attribute__((ext_vector_type(4)));
typedef unsigned int u32x4 __attribute__((ext_vector_type(4)));

#define MFMA_K32(a, b, c) __builtin_amdgcn_mfma_f32_16x16x32_bf16((a), (b), (c), 0, 0, 0)
#define MFMA_K16(a, b, c) __builtin_amdgcn_mfma_f32_16x16x16bf16_1k((a), (b), (c), 0, 0, 0)

// pack two fp32 -> two bf16 (round-half-up) in one u32 (R1-verified)
__device__ __forceinline__ unsigned pk2(float lo, float hi) {
  return __builtin_amdgcn_perm(__float_as_uint(hi) + 0x8000u,
                               __float_as_uint(lo) + 0x8000u, 0x07060302u);
}
__device__ __forceinline__ unsigned short bf1(float v) {
  return (unsigned short)((__float_as_uint(v) + 0x8000u) >> 16);
}
__device__ __forceinline__ bf16x4 pack4(float a, float b, float c, float d) {
  union { unsigned u[2]; bf16x4 h; } r;
  r.u[0] = pk2(a, b); r.u[1] = pk2(c, d);
  return r.h;
}

// ---- workspace layout (bytes) ----
#define OFF_QKVT  0u        // bf16 [384][128] W^T (col-major W), q-scale folded
#define OFF_PROJT 98304u    // bf16 [128][128] W^T
#define OFF_BIAST 131072u   // f32  [4][16 k4][64 q][4 ki]  vectorized rel-pos bias
#define OFF_BSC   196608u   // f32  [384] qkv_b (q part scaled)

__global__ void prep_kernel(const float* __restrict__ qkv_w,
                            const float* __restrict__ qkv_b,
                            const float* __restrict__ proj_w,
                            const float* __restrict__ bias_table,
                            const int*   __restrict__ rel_index,
                            char* __restrict__ ws) {
  const float scale = 0.17677669529663687f;  // 32^-0.5
  int idx = blockIdx.x * 256 + threadIdx.x;
  if (idx < 49152) {
    int n = idx >> 7, k = idx & 127;
    float v = qkv_w[k * 384 + n];
    if (n < 128) v *= scale;
    ((unsigned short*)(ws + OFF_QKVT))[idx] = bf1(v);
  } else if (idx < 65536) {
    int j = idx - 49152;
    int n = j >> 7, k = j & 127;
    ((unsigned short*)(ws + OFF_PROJT))[j] = bf1(proj_w[k * 128 + n]);
  } else if (idx < 75140) {                    // biasP[h][key>>2][q][key&3]
    int j = idx - 65536;
    int h = j / 2401, rem = j % 2401;
    int key = rem / 49, q = rem - key * 49;
    ((float*)(ws + OFF_BIAST))[h * 4096 + (key >> 2) * 256 + q * 4 + (key & 3)]
        = bias_table[rel_index[q * 49 + key] * 4 + h];
  } else if (idx < 75524) {
    int j = idx - 75140;
    float v = qkv_b[j];
    if (j < 128) v *= scale;
    ((float*)(ws + OFF_BSC))[j] = v;
  }
}

// LDS: [0,33792)       xs fp32 [64 tok][528B row], byte = tok*528 + col (no XOR;
//                      stride 528 = 132 words ≡ 4 mod 32 banks -> ~2-way reads).
//                      Rows 49..63 zeroed. First 16KB reused as `mid` bf16
//                      [64][256B] (byte = tok*256 + (2d ^ ((tok&15)<<4))).
//      [33792,50432)   mask f32 [16 k4][1040B]: byte = k4*1040 + q*16 + ki*4
//                      (OOB slots garbage — discarded by the bounds select)
#define XSTR 528u
#define MSK  33792u

__global__ __launch_bounds__(256, 3)
void win_attn_kernel(const float* __restrict__ x,
                     const float* __restrict__ mask,
                     const float* __restrict__ proj_b,
                     const char*  __restrict__ ws,
                     float* __restrict__ out) {
  __shared__ __align__(16) char smem[50432];
  const int b    = blockIdx.x;
  const int tid  = threadIdx.x;
  const int w    = tid >> 6;        // wave id == head id
  const int lane = tid & 63;
  const int l16  = lane & 15;
  const int lg   = lane >> 4;

  const unsigned short* qkvT  = (const unsigned short*)(ws + OFF_QKVT);
  const unsigned short* projT = (const unsigned short*)(ws + OFF_PROJT);
  const float* bp  = (const float*)(ws + OFF_BIAST) + w * 4096;  // [k4][q][ki]
  const float* bsc = (const float*)(ws + OFF_BSC);

  // ============ stage x (fp32, stride-528) + mask (stride-1040) -> LDS ============
  {
    const float* xb = x + (size_t)b * 6272;
#pragma unroll
    for (int it = 0; it < 8; ++it) {
      int idx = tid + it * 256;                // 2048 chunks of 16B: tok*32+c
      int tok = idx >> 5, c = idx & 31;
      unsigned off = (unsigned)tok * XSTR + (unsigned)c * 16u;
      if (tok < 49) {
        *(float4*)(smem + off) = *(const float4*)(xb + tok * 128 + c * 4);
      } else {
        *(float4*)(smem + off) = make_float4(0.f, 0.f, 0.f, 0.f);
      }
    }
    const float* mb = mask + (size_t)b * 2401;
#pragma unroll
    for (int it = 0; it < 10; ++it) {
      int i = tid + it * 256;
      if (i < 2401) {
        int q = i / 49, key = i - q * 49;
        unsigned off = MSK + (unsigned)(key >> 2) * 1040u +
                       (unsigned)q * 16u + ((unsigned)key & 3u) * 4u;
        *(float*)(smem + off) = mb[i];
      }
    }
  }
  __syncthreads();

  // x fragment from LDS (lane = token l16), pack fp32->bf16 at read
  auto xfrag = [&](int tt, int ks) -> bf16x8 {
    int tok = 16 * tt + l16;
    unsigned off = (unsigned)tok * XSTR + (unsigned)(128 * ks + 32 * lg);
    float4 v0 = *(const float4*)(smem + off);
    float4 v1 = *(const float4*)(smem + off + 16);
    union { u32x4 u; bf16x8 h; } pk;
    pk.u.x = pk2(v0.x, v0.y); pk.u.y = pk2(v0.z, v0.w);
    pk.u.z = pk2(v1.x, v1.y); pk.u.w = pk2(v1.z, v1.w);
    return pk.h;
  };

  // ============ GEMM1 pass A: Q^T,K^T tiles = mfma(W^T-frag, x-frag) ============
  f32x4 qt_acc[2][4], kt_acc[2][4];
#pragma unroll
  for (int dt = 0; dt < 2; ++dt) {
    f32x4 qb, kb;
#pragma unroll
    for (int i = 0; i < 4; ++i) {
      qb[i] = bsc[32 * w + 16 * dt + 4 * lg + i];
      kb[i] = bsc[128 + 32 * w + 16 * dt + 4 * lg + i];
    }
#pragma unroll
    for (int tt = 0; tt < 4; ++tt) { qt_acc[dt][tt] = qb; kt_acc[dt][tt] = kb; }
  }
#pragma unroll
  for (int ks = 0; ks < 4; ++ks) {
    bf16x8 xf[4];
#pragma unroll
    for (int tt = 0; tt < 4; ++tt) xf[tt] = xfrag(tt, ks);
#pragma unroll
    for (int dt = 0; dt < 2; ++dt) {
      bf16x8 wq = *(const bf16x8*)(qkvT + (size_t)(32 * w + 16 * dt + l16) * 128 + 32 * ks + 8 * lg);
      bf16x8 wk = *(const bf16x8*)(qkvT + (size_t)(128 + 32 * w + 16 * dt + l16) * 128 + 32 * ks + 8 * lg);
#pragma unroll
      for (int tt = 0; tt < 4; ++tt) {
        qt_acc[dt][tt] = MFMA_K32(wq, xf[tt], qt_acc[dt][tt]);
        kt_acc[dt][tt] = MFMA_K32(wk, xf[tt], kt_acc[dt][tt]);
      }
    }
  }
  bf16x4 qf[4][2], kf[4][2];
#pragma unroll
  for (int tt = 0; tt < 4; ++tt)
#pragma unroll
    for (int dt = 0; dt < 2; ++dt) {
      qf[tt][dt] = pack4(qt_acc[dt][tt][0], qt_acc[dt][tt][1], qt_acc[dt][tt][2], qt_acc[dt][tt][3]);
      kf[tt][dt] = pack4(kt_acc[dt][tt][0], kt_acc[dt][tt][1], kt_acc[dt][tt][2], kt_acc[dt][tt][3]);
    }

  // ============ GEMM1 pass B: V tiles = mfma(x-frag, Wv^T-frag) ============
  f32x4 v_acc[4][2];
  {
    float vb0 = bsc[256 + 32 * w + l16];
    float vb1 = bsc[256 + 32 * w + 16 + l16];
#pragma unroll
    for (int tt = 0; tt < 4; ++tt) {
      v_acc[tt][0] = (f32x4){vb0, vb0, vb0, vb0};
      v_acc[tt][1] = (f32x4){vb1, vb1, vb1, vb1};
    }
  }
#pragma unroll
  for (int ks = 0; ks < 4; ++ks) {
    bf16x8 xf[4];
#pragma unroll
    for (int tt = 0; tt < 4; ++tt) xf[tt] = xfrag(tt, ks);   // LDS re-read, cheap
#pragma unroll
    for (int dt = 0; dt < 2; ++dt) {
      bf16x8 wv = *(const bf16x8*)(qkvT + (size_t)(256 + 32 * w + 16 * dt + l16) * 128 + 32 * ks + 8 * lg);
#pragma unroll
      for (int tt = 0; tt < 4; ++tt) v_acc[tt][dt] = MFMA_K32(xf[tt], wv, v_acc[tt][dt]);
    }
  }
  bf16x4 vf[2][4];
#pragma unroll
  for (int dt = 0; dt < 2; ++dt)
#pragma unroll
    for (int tt = 0; tt < 4; ++tt)
      vf[dt][tt] = pack4(v_acc[tt][dt][0], v_acc[tt][dt][1], v_acc[tt][dt][2], v_acc[tt][dt][3]);

  __syncthreads();   // all waves done reading xs; first 16KB becomes `mid`

  // ============ QK^T (K=16): S^T[key][q] tiles, lane = q, regs = key ============
  f32x4 s_acc[4][4];  // [kt][qt]
#pragma unroll
  for (int kt = 0; kt < 4; ++kt)
#pragma unroll
    for (int qt = 0; qt < 4; ++qt) s_acc[kt][qt] = (f32x4){0.f, 0.f, 0.f, 0.f};
#pragma unroll
  for (int kt = 0; kt < 4; ++kt)
#pragma unroll
    for (int qt = 0; qt < 4; ++qt) {
      s_acc[kt][qt] = MFMA_K16(kf[kt][0], qf[qt][0], s_acc[kt][qt]);
      s_acc[kt][qt] = MFMA_K16(kf[kt][1], qf[qt][1], s_acc[kt][qt]);
    }

  // ====== bias (float4, coalesced) + mask (LDS, ~2-way) + no-max softmax ======
  float rs_[4];
#pragma unroll
  for (int qt = 0; qt < 4; ++qt) {
    int q = 16 * qt + l16;
    bool qok = q < 49;
    float sum = 0.f;
#pragma unroll
    for (int kt = 0; kt < 4; ++kt) {
      int k4 = 4 * kt + lg;
      float4 bv = *(const float4*)(bp + k4 * 256 + q * 4);
      float4 mk = *(const float4*)(smem + MSK + (unsigned)k4 * 1040u + (unsigned)q * 16u);
      float ba[4] = {bv.x + mk.x, bv.y + mk.y, bv.z + mk.z, bv.w + mk.w};
#pragma unroll
      for (int i = 0; i < 4; ++i) {
        int key = 16 * kt + 4 * lg + i;
        float v = s_acc[kt][qt][i];
        v = (qok && key < 49) ? (v + ba[i]) : -30000.0f;
        float e = __expf(v - 8.0f);
        s_acc[kt][qt][i] = e;
        sum += e;
      }
    }
    sum += __shfl_xor(sum, 16);
    sum += __shfl_xor(sum, 32);
    rs_[qt] = 1.0f / (sum + 1e-30f);   // padded rows: sum==0 -> rs finite
  }

  // ============ P frags in-register; PV (K=16): O^T[d][q], lane = q ============
  bf16x4 pf[4][4];  // [qt][kt]
#pragma unroll
  for (int qt = 0; qt < 4; ++qt)
#pragma unroll
    for (int kt = 0; kt < 4; ++kt)
      pf[qt][kt] = pack4(s_acc[kt][qt][0], s_acc[kt][qt][1], s_acc[kt][qt][2], s_acc[kt][qt][3]);

  f32x4 o_acc[2][4];  // [dt][qt]: lane = q, regs = d = 4lg+i
#pragma unroll
  for (int dt = 0; dt < 2; ++dt)
#pragma unroll
    for (int qt = 0; qt < 4; ++qt) o_acc[dt][qt] = (f32x4){0.f, 0.f, 0.f, 0.f};
#pragma unroll
  for (int kt = 0; kt < 4; ++kt)
#pragma unroll
    for (int dt = 0; dt < 2; ++dt)
#pragma unroll
      for (int qt = 0; qt < 4; ++qt)
        o_acc[dt][qt] = MFMA_K16(vf[dt][kt], pf[qt][kt], o_acc[dt][qt]);

  // ============ normalize + write mid[q][32w+16dt+4lg..+3] (uint2) ============
#pragma unroll
  for (int qt = 0; qt < 4; ++qt) {
    int q = 16 * qt + l16;
    float r = rs_[qt];
    unsigned rowb = (unsigned)q * 256u, sw = ((unsigned)q & 15u) << 4;
#pragma unroll
    for (int dt = 0; dt < 2; ++dt) {
      unsigned u0 = pk2(o_acc[dt][qt][0] * r, o_acc[dt][qt][1] * r);
      unsigned u1 = pk2(o_acc[dt][qt][2] * r, o_acc[dt][qt][3] * r);
      unsigned L = (unsigned)(64 * w + 32 * dt + 8 * lg);
      *(uint2*)(smem + rowb + (L ^ sw)) = make_uint2(u0, u1);
    }
  }
  __syncthreads();

  // ==== GEMM2 swapped (K=32): out^T tiles = mfma(projW-frag, mid-frag) ====
  // C rows (regs) = out-col c = 32w+16nt+4lg+i ; C cols (lane) = tok = 16mt+l16.
  // Epilogue: 8 predicated float4 stores (was 32 scalar + 32 checks).
  f32x4 c2[2][4];  // [nt][mt]
#pragma unroll
  for (int nt = 0; nt < 2; ++nt) {
    f32x4 pbv;
#pragma unroll
    for (int i = 0; i < 4; ++i) pbv[i] = proj_b[32 * w + 16 * nt + 4 * lg + i];
#pragma unroll
    for (int mt = 0; mt < 4; ++mt) c2[nt][mt] = pbv;
  }
#pragma unroll
  for (int ks = 0; ks < 4; ++ks) {
    bf16x8 a2[4];
#pragma unroll
    for (int mt = 0; mt < 4; ++mt) {
      int tok = 16 * mt + l16;
      unsigned byte = (unsigned)tok * 256u +
                      (((unsigned)(64 * ks + 16 * lg)) ^ (((unsigned)tok & 15u) << 4));
      a2[mt] = *(const bf16x8*)(smem + byte);
    }
#pragma unroll
    for (int nt = 0; nt < 2; ++nt) {
      bf16x8 b2 = *(const bf16x8*)(projT + (size_t)(32 * w + 16 * nt + l16) * 128 + 32 * ks + 8 * lg);
#pragma unroll
      for (int mt = 0; mt < 4; ++mt) c2[nt][mt] = MFMA_K32(b2, a2[mt], c2[nt][mt]);
    }
  }
  float* ob = out + (size_t)b * 6272;
#pragma unroll
  for (int mt = 0; mt < 4; ++mt) {
    int tok = 16 * mt + l16;
    if (tok < 49) {
#pragma unroll
      for (int nt = 0; nt < 2; ++nt) {
        float4 v = make_float4(c2[nt][mt][0], c2[nt][mt][1], c2[nt][mt][2], c2[nt][mt][3]);
        *(float4*)(ob + tok * 128 + 32 * w + 16 * nt + 4 * lg) = v;
      }
    }
  }
}

extern "C" void kernel_launch(void* const* d_in, const int* in_sizes, int n_in,
                              void* d_out, int out_size, void* d_ws, size_t ws_size,
                              hipStream_t stream) {
  const float* x          = (const float*)d_in[0];
  const float* mask       = (const float*)d_in[1];
  const float* qkv_w      = (const float*)d_in[2];
  const float* qkv_b      = (const float*)d_in[3];
  const float* proj_w     = (const float*)d_in[4];
  const float* proj_b     = (const float*)d_in[5];
  const float* bias_table = (const float*)d_in[6];
  const int*   rel_index  = (const int*)d_in[7];
  char* ws = (char*)d_ws;

  prep_kernel<<<296, 256, 0, stream>>>(qkv_w, qkv_b, proj_w, bias_table, rel_index, ws);
  win_attn_kernel<<<4096, 256, 0, stream>>>(x, mask, proj_b, ws, (float*)d_out);
}

// Round 20
// 103.401 us; speedup vs baseline: 5.5739x; 1.1900x over previous
//
#include <hip/hip_runtime.h>

// WindowAttention fused, MI355X gfx950 — R19: exact R14 base (116us best) +
// ONE change: W matrices re-laid as [k-chunk][n][8k] so every W-fragment load
// is lane-coalesced (2 cache lines/instr instead of 16-line gather).
// B=4096 windows, N=49 (pad 64), C=128, H=4 heads, d=32. wave w = head w.

typedef short bf16x4 __attribute__((ext_vector_type(4)));
typedef short bf16x8 __attribute__((ext_vector_type(8)));
typedef float f32x4 __attribute__((ext_vector_type(4)));
typedef unsigned int u32x4 __attribute__((ext_vector_type(4)));

#define MFMA_K32(a, b, c) __builtin_amdgcn_mfma_f32_16x16x32_bf16((a), (b), (c), 0, 0, 0)
#define MFMA_K16(a, b, c) __builtin_amdgcn_mfma_f32_16x16x16bf16_1k((a), (b), (c), 0, 0, 0)

// pack two fp32 -> two bf16 (round-half-up) in one u32 (R1-verified)
__device__ __forceinline__ unsigned pk2(float lo, float hi) {
  return __builtin_amdgcn_perm(__float_as_uint(hi) + 0x8000u,
                               __float_as_uint(lo) + 0x8000u, 0x07060302u);
}
__device__ __forceinline__ unsigned short bf1(float v) {
  return (unsigned short)((__float_as_uint(v) + 0x8000u) >> 16);
}
__device__ __forceinline__ bf16x4 pack4(float a, float b, float c, float d) {
  union { unsigned u[2]; bf16x4 h; } r;
  r.u[0] = pk2(a, b); r.u[1] = pk2(c, d);
  return r.h;
}

// ---- workspace layout (bytes) ----
// qkvP : bf16 [16 kc][384 n][8 k]  (k-chunk-major; q-scale folded into n<128)
// projP: bf16 [16 kc][128 n][8 k]
// biasP: f32  [4][16 k4][64 q][4 ki]
// bsc  : f32  [384] qkv_b (q part scaled)
#define OFF_QKVT  0u
#define OFF_PROJT 98304u
#define OFF_BIAST 131072u
#define OFF_BSC   196608u

__global__ void prep_kernel(const float* __restrict__ qkv_w,
                            const float* __restrict__ qkv_b,
                            const float* __restrict__ proj_w,
                            const float* __restrict__ bias_table,
                            const int*   __restrict__ rel_index,
                            char* __restrict__ ws) {
  const float scale = 0.17677669529663687f;  // 32^-0.5
  int idx = blockIdx.x * 256 + threadIdx.x;
  if (idx < 49152) {                 // qkvP[((k>>3)*384 + n)*8 + (k&7)] = w[k][n]
    int n = idx >> 7, k = idx & 127;
    float v = qkv_w[k * 384 + n];
    if (n < 128) v *= scale;
    ((unsigned short*)(ws + OFF_QKVT))[(((k >> 3) * 384) + n) * 8 + (k & 7)] = bf1(v);
  } else if (idx < 65536) {          // projP[((k>>3)*128 + n)*8 + (k&7)] = w[k][n]
    int j = idx - 49152;
    int n = j >> 7, k = j & 127;
    ((unsigned short*)(ws + OFF_PROJT))[(((k >> 3) * 128) + n) * 8 + (k & 7)] = bf1(proj_w[k * 128 + n]);
  } else if (idx < 75140) {          // biasP[h][key>>2][q][key&3]
    int j = idx - 65536;
    int h = j / 2401, rem = j % 2401;
    int key = rem / 49, q = rem - key * 49;
    ((float*)(ws + OFF_BIAST))[h * 4096 + (key >> 2) * 256 + q * 4 + (key & 3)]
        = bias_table[rel_index[q * 49 + key] * 4 + h];
  } else if (idx < 75524) {
    int j = idx - 75140;
    float v = qkv_b[j];
    if (j < 128) v *= scale;
    ((float*)(ws + OFF_BSC))[j] = v;
  }
}

// LDS: [0,33792)       xs fp32 [64 tok][528B row], byte = tok*528 + col (no XOR;
//                      stride 528 = 132 words ≡ 4 mod 32 banks -> ~2-way reads).
//                      Rows 49..63 zeroed. First 16KB reused as `mid` bf16
//                      [64][256B] (byte = tok*256 + (2d ^ ((tok&15)<<4))).
//      [33792,50432)   mask f32 [16 k4][1040B]: byte = k4*1040 + q*16 + ki*4
//                      (OOB slots garbage — discarded by the bounds select)
#define XSTR 528u
#define MSK  33792u

__global__ __launch_bounds__(256, 3)
void win_attn_kernel(const float* __restrict__ x,
                     const float* __restrict__ mask,
                     const float* __restrict__ proj_b,
                     const char*  __restrict__ ws,
                     float* __restrict__ out) {
  __shared__ __align__(16) char smem[50432];
  const int b    = blockIdx.x;
  const int tid  = threadIdx.x;
  const int w    = tid >> 6;        // wave id == head id
  const int lane = tid & 63;
  const int l16  = lane & 15;
  const int lg   = lane >> 4;

  const unsigned short* qkvP  = (const unsigned short*)(ws + OFF_QKVT);
  const unsigned short* projP = (const unsigned short*)(ws + OFF_PROJT);
  const float* bp  = (const float*)(ws + OFF_BIAST) + w * 4096;  // [k4][q][ki]
  const float* bsc = (const float*)(ws + OFF_BSC);

  // ============ stage x (fp32, stride-528) + mask (stride-1040) -> LDS ============
  {
    const float* xb = x + (size_t)b * 6272;
#pragma unroll
    for (int it = 0; it < 8; ++it) {
      int idx = tid + it * 256;                // 2048 chunks of 16B: tok*32+c
      int tok = idx >> 5, c = idx & 31;
      unsigned off = (unsigned)tok * XSTR + (unsigned)c * 16u;
      if (tok < 49) {
        *(float4*)(smem + off) = *(const float4*)(xb + tok * 128 + c * 4);
      } else {
        *(float4*)(smem + off) = make_float4(0.f, 0.f, 0.f, 0.f);
      }
    }
    const float* mb = mask + (size_t)b * 2401;
#pragma unroll
    for (int it = 0; it < 10; ++it) {
      int i = tid + it * 256;
      if (i < 2401) {
        int q = i / 49, key = i - q * 49;
        unsigned off = MSK + (unsigned)(key >> 2) * 1040u +
                       (unsigned)q * 16u + ((unsigned)key & 3u) * 4u;
        *(float*)(smem + off) = mb[i];
      }
    }
  }
  __syncthreads();

  // x fragment from LDS (lane = token l16), pack fp32->bf16 at read
  auto xfrag = [&](int tt, int ks) -> bf16x8 {
    int tok = 16 * tt + l16;
    unsigned off = (unsigned)tok * XSTR + (unsigned)(128 * ks + 32 * lg);
    float4 v0 = *(const float4*)(smem + off);
    float4 v1 = *(const float4*)(smem + off + 16);
    union { u32x4 u; bf16x8 h; } pk;
    pk.u.x = pk2(v0.x, v0.y); pk.u.y = pk2(v0.z, v0.w);
    pk.u.z = pk2(v1.x, v1.y); pk.u.w = pk2(v1.z, v1.w);
    return pk.h;
  };

  // coalesced W fragment: k-chunk kc = 4ks+lg, rows n..n+15 consecutive
  auto wfrag = [&](const unsigned short* base, int N, int kc, int n) -> bf16x8 {
    return *(const bf16x8*)(base + ((size_t)kc * N + n) * 8);
  };

  // ============ GEMM1 pass A: Q^T,K^T tiles = mfma(W^T-frag, x-frag) ============
  f32x4 qt_acc[2][4], kt_acc[2][4];
#pragma unroll
  for (int dt = 0; dt < 2; ++dt) {
    f32x4 qb, kb;
#pragma unroll
    for (int i = 0; i < 4; ++i) {
      qb[i] = bsc[32 * w + 16 * dt + 4 * lg + i];
      kb[i] = bsc[128 + 32 * w + 16 * dt + 4 * lg + i];
    }
#pragma unroll
    for (int tt = 0; tt < 4; ++tt) { qt_acc[dt][tt] = qb; kt_acc[dt][tt] = kb; }
  }
#pragma unroll
  for (int ks = 0; ks < 4; ++ks) {
    int kc = 4 * ks + lg;
    bf16x8 xf[4];
#pragma unroll
    for (int tt = 0; tt < 4; ++tt) xf[tt] = xfrag(tt, ks);
#pragma unroll
    for (int dt = 0; dt < 2; ++dt) {
      bf16x8 wq = wfrag(qkvP, 384, kc, 32 * w + 16 * dt + l16);
      bf16x8 wk = wfrag(qkvP, 384, kc, 128 + 32 * w + 16 * dt + l16);
#pragma unroll
      for (int tt = 0; tt < 4; ++tt) {
        qt_acc[dt][tt] = MFMA_K32(wq, xf[tt], qt_acc[dt][tt]);
        kt_acc[dt][tt] = MFMA_K32(wk, xf[tt], kt_acc[dt][tt]);
      }
    }
  }
  bf16x4 qf[4][2], kf[4][2];
#pragma unroll
  for (int tt = 0; tt < 4; ++tt)
#pragma unroll
    for (int dt = 0; dt < 2; ++dt) {
      qf[tt][dt] = pack4(qt_acc[dt][tt][0], qt_acc[dt][tt][1], qt_acc[dt][tt][2], qt_acc[dt][tt][3]);
      kf[tt][dt] = pack4(kt_acc[dt][tt][0], kt_acc[dt][tt][1], kt_acc[dt][tt][2], kt_acc[dt][tt][3]);
    }

  // ============ GEMM1 pass B: V tiles = mfma(x-frag, Wv^T-frag) ============
  f32x4 v_acc[4][2];
  {
    float vb0 = bsc[256 + 32 * w + l16];
    float vb1 = bsc[256 + 32 * w + 16 + l16];
#pragma unroll
    for (int tt = 0; tt < 4; ++tt) {
      v_acc[tt][0] = (f32x4){vb0, vb0, vb0, vb0};
      v_acc[tt][1] = (f32x4){vb1, vb1, vb1, vb1};
    }
  }
#pragma unroll
  for (int ks = 0; ks < 4; ++ks) {
    int kc = 4 * ks + lg;
    bf16x8 xf[4];
#pragma unroll
    for (int tt = 0; tt < 4; ++tt) xf[tt] = xfrag(tt, ks);   // LDS re-read, cheap
#pragma unroll
    for (int dt = 0; dt < 2; ++dt) {
      bf16x8 wv = wfrag(qkvP, 384, kc, 256 + 32 * w + 16 * dt + l16);
#pragma unroll
      for (int tt = 0; tt < 4; ++tt) v_acc[tt][dt] = MFMA_K32(xf[tt], wv, v_acc[tt][dt]);
    }
  }
  bf16x4 vf[2][4];
#pragma unroll
  for (int dt = 0; dt < 2; ++dt)
#pragma unroll
    for (int tt = 0; tt < 4; ++tt)
      vf[dt][tt] = pack4(v_acc[tt][dt][0], v_acc[tt][dt][1], v_acc[tt][dt][2], v_acc[tt][dt][3]);

  __syncthreads();   // all waves done reading xs; first 16KB becomes `mid`

  // ============ QK^T (K=16): S^T[key][q] tiles, lane = q, regs = key ============
  f32x4 s_acc[4][4];  // [kt][qt]
#pragma unroll
  for (int kt = 0; kt < 4; ++kt)
#pragma unroll
    for (int qt = 0; qt < 4; ++qt) s_acc[kt][qt] = (f32x4){0.f, 0.f, 0.f, 0.f};
#pragma unroll
  for (int kt = 0; kt < 4; ++kt)
#pragma unroll
    for (int qt = 0; qt < 4; ++qt) {
      s_acc[kt][qt] = MFMA_K16(kf[kt][0], qf[qt][0], s_acc[kt][qt]);
      s_acc[kt][qt] = MFMA_K16(kf[kt][1], qf[qt][1], s_acc[kt][qt]);
    }

  // ====== bias (float4, coalesced) + mask (LDS, ~2-way) + no-max softmax ======
  float rs_[4];
#pragma unroll
  for (int qt = 0; qt < 4; ++qt) {
    int q = 16 * qt + l16;
    bool qok = q < 49;
    float sum = 0.f;
#pragma unroll
    for (int kt = 0; kt < 4; ++kt) {
      int k4 = 4 * kt + lg;
      float4 bv = *(const float4*)(bp + k4 * 256 + q * 4);
      float4 mk = *(const float4*)(smem + MSK + (unsigned)k4 * 1040u + (unsigned)q * 16u);
      float ba[4] = {bv.x + mk.x, bv.y + mk.y, bv.z + mk.z, bv.w + mk.w};
#pragma unroll
      for (int i = 0; i < 4; ++i) {
        int key = 16 * kt + 4 * lg + i;
        float v = s_acc[kt][qt][i];
        v = (qok && key < 49) ? (v + ba[i]) : -30000.0f;
        float e = __expf(v - 8.0f);
        s_acc[kt][qt][i] = e;
        sum += e;
      }
    }
    sum += __shfl_xor(sum, 16);
    sum += __shfl_xor(sum, 32);
    rs_[qt] = 1.0f / (sum + 1e-30f);   // padded rows: sum==0 -> rs finite
  }

  // ============ P frags in-register; PV (K=16): O^T[d][q], lane = q ============
  bf16x4 pf[4][4];  // [qt][kt]
#pragma unroll
  for (int qt = 0; qt < 4; ++qt)
#pragma unroll
    for (int kt = 0; kt < 4; ++kt)
      pf[qt][kt] = pack4(s_acc[kt][qt][0], s_acc[kt][qt][1], s_acc[kt][qt][2], s_acc[kt][qt][3]);

  f32x4 o_acc[2][4];  // [dt][qt]: lane = q, regs = d = 4lg+i
#pragma unroll
  for (int dt = 0; dt < 2; ++dt)
#pragma unroll
    for (int qt = 0; qt < 4; ++qt) o_acc[dt][qt] = (f32x4){0.f, 0.f, 0.f, 0.f};
#pragma unroll
  for (int kt = 0; kt < 4; ++kt)
#pragma unroll
    for (int dt = 0; dt < 2; ++dt)
#pragma unroll
      for (int qt = 0; qt < 4; ++qt)
        o_acc[dt][qt] = MFMA_K16(vf[dt][kt], pf[qt][kt], o_acc[dt][qt]);

  // ============ normalize + write mid[q][32w+16dt+4lg..+3] (uint2) ============
#pragma unroll
  for (int qt = 0; qt < 4; ++qt) {
    int q = 16 * qt + l16;
    float r = rs_[qt];
    unsigned rowb = (unsigned)q * 256u, sw = ((unsigned)q & 15u) << 4;
#pragma unroll
    for (int dt = 0; dt < 2; ++dt) {
      unsigned u0 = pk2(o_acc[dt][qt][0] * r, o_acc[dt][qt][1] * r);
      unsigned u1 = pk2(o_acc[dt][qt][2] * r, o_acc[dt][qt][3] * r);
      unsigned L = (unsigned)(64 * w + 32 * dt + 8 * lg);
      *(uint2*)(smem + rowb + (L ^ sw)) = make_uint2(u0, u1);
    }
  }
  __syncthreads();

  // ============ GEMM2 (K=32): out = mid @ projW + b; wave w: cols 32w..32w+31 ============
  f32x4 c2[2][4];
#pragma unroll
  for (int nt = 0; nt < 2; ++nt) {
    float pbv = proj_b[32 * w + 16 * nt + l16];
#pragma unroll
    for (int mt = 0; mt < 4; ++mt) c2[nt][mt] = (f32x4){pbv, pbv, pbv, pbv};
  }
#pragma unroll
  for (int ks = 0; ks < 4; ++ks) {
    int kc = 4 * ks + lg;
    bf16x8 a2[4];
#pragma unroll
    for (int mt = 0; mt < 4; ++mt) {
      int tok = 16 * mt + l16;
      unsigned byte = (unsigned)tok * 256u +
                      (((unsigned)(64 * ks + 16 * lg)) ^ (((unsigned)tok & 15u) << 4));
      a2[mt] = *(const bf16x8*)(smem + byte);
    }
#pragma unroll
    for (int nt = 0; nt < 2; ++nt) {
      bf16x8 b2 = wfrag(projP, 128, kc, 32 * w + 16 * nt + l16);
#pragma unroll
      for (int mt = 0; mt < 4; ++mt) c2[nt][mt] = MFMA_K32(a2[mt], b2, c2[nt][mt]);
    }
  }
  float* ob = out + (size_t)b * 6272;
#pragma unroll
  for (int mt = 0; mt < 4; ++mt)
#pragma unroll
    for (int nt = 0; nt < 2; ++nt)
#pragma unroll
      for (int i = 0; i < 4; ++i) {
        int r = 16 * mt + 4 * lg + i;
        if (r < 49) ob[r * 128 + 32 * w + 16 * nt + l16] = c2[nt][mt][i];
      }
}

extern "C" void kernel_launch(void* const* d_in, const int* in_sizes, int n_in,
                              void* d_out, int out_size, void* d_ws, size_t ws_size,
                              hipStream_t stream) {
  const float* x          = (const float*)d_in[0];
  const float* mask       = (const float*)d_in[1];
  const float* qkv_w      = (const float*)d_in[2];
  const float* qkv_b      = (const float*)d_in[3];
  const float* proj_w     = (const float*)d_in[4];
  const float* proj_b     = (const float*)d_in[5];
  const float* bias_table = (const float*)d_in[6];
  const int*   rel_index  = (const int*)d_in[7];
  char* ws = (char*)d_ws;

  prep_kernel<<<296, 256, 0, stream>>>(qkv_w, qkv_b, proj_w, bias_table, rel_index, ws);
  win_attn_kernel<<<4096, 256, 0, stream>>>(x, mask, proj_b, ws, (float*)d_out);
}

// Round 21
// 101.307 us; speedup vs baseline: 5.6891x; 1.0207x over previous
//
#include <hip/hip_runtime.h>

// WindowAttention fused, MI355X gfx950 — R20: R19 (103us best) + xs addressing
// reverted to the R12-verified 512B+XOR layout (2.8M conflict-cycles vs 528B's
// 4.3M). Keeps R19's coalesced W layout + R14's mask stride-1040.
// B=4096 windows, N=49 (pad 64), C=128, H=4 heads, d=32. wave w = head w.

typedef short bf16x4 __attribute__((ext_vector_type(4)));
typedef short bf16x8 __attribute__((ext_vector_type(8)));
typedef float f32x4 __attribute__((ext_vector_type(4)));
typedef unsigned int u32x4 __attribute__((ext_vector_type(4)));

#define MFMA_K32(a, b, c) __builtin_amdgcn_mfma_f32_16x16x32_bf16((a), (b), (c), 0, 0, 0)
#define MFMA_K16(a, b, c) __builtin_amdgcn_mfma_f32_16x16x16bf16_1k((a), (b), (c), 0, 0, 0)

// pack two fp32 -> two bf16 (round-half-up) in one u32 (R1-verified)
__device__ __forceinline__ unsigned pk2(float lo, float hi) {
  return __builtin_amdgcn_perm(__float_as_uint(hi) + 0x8000u,
                               __float_as_uint(lo) + 0x8000u, 0x07060302u);
}
__device__ __forceinline__ unsigned short bf1(float v) {
  return (unsigned short)((__float_as_uint(v) + 0x8000u) >> 16);
}
__device__ __forceinline__ bf16x4 pack4(float a, float b, float c, float d) {
  union { unsigned u[2]; bf16x4 h; } r;
  r.u[0] = pk2(a, b); r.u[1] = pk2(c, d);
  return r.h;
}

// ---- workspace layout (bytes) ----
// qkvP : bf16 [16 kc][384 n][8 k]  (k-chunk-major; q-scale folded into n<128)
// projP: bf16 [16 kc][128 n][8 k]
// biasP: f32  [4][16 k4][64 q][4 ki]
// bsc  : f32  [384] qkv_b (q part scaled)
#define OFF_QKVT  0u
#define OFF_PROJT 98304u
#define OFF_BIAST 131072u
#define OFF_BSC   196608u

__global__ void prep_kernel(const float* __restrict__ qkv_w,
                            const float* __restrict__ qkv_b,
                            const float* __restrict__ proj_w,
                            const float* __restrict__ bias_table,
                            const int*   __restrict__ rel_index,
                            char* __restrict__ ws) {
  const float scale = 0.17677669529663687f;  // 32^-0.5
  int idx = blockIdx.x * 256 + threadIdx.x;
  if (idx < 49152) {                 // qkvP[((k>>3)*384 + n)*8 + (k&7)] = w[k][n]
    int n = idx >> 7, k = idx & 127;
    float v = qkv_w[k * 384 + n];
    if (n < 128) v *= scale;
    ((unsigned short*)(ws + OFF_QKVT))[(((k >> 3) * 384) + n) * 8 + (k & 7)] = bf1(v);
  } else if (idx < 65536) {          // projP[((k>>3)*128 + n)*8 + (k&7)] = w[k][n]
    int j = idx - 49152;
    int n = j >> 7, k = j & 127;
    ((unsigned short*)(ws + OFF_PROJT))[(((k >> 3) * 128) + n) * 8 + (k & 7)] = bf1(proj_w[k * 128 + n]);
  } else if (idx < 75140) {          // biasP[h][key>>2][q][key&3]
    int j = idx - 65536;
    int h = j / 2401, rem = j % 2401;
    int key = rem / 49, q = rem - key * 49;
    ((float*)(ws + OFF_BIAST))[h * 4096 + (key >> 2) * 256 + q * 4 + (key & 3)]
        = bias_table[rel_index[q * 49 + key] * 4 + h];
  } else if (idx < 75524) {
    int j = idx - 75140;
    float v = qkv_b[j];
    if (j < 128) v *= scale;
    ((float*)(ws + OFF_BSC))[j] = v;
  }
}

// LDS: [0,32768)       xs fp32 [64 tok][512B row], byte = tok*512 + (col ^ ((tok&15)<<5))
//                      (R12-verified; ~2-way reads). Rows 49..63 zeroed. First
//                      16KB reused as `mid` bf16 [64][256B]
//                      (byte = tok*256 + (2d ^ ((tok&15)<<4))).
//      [32768,49408)   mask f32 [16 k4][1040B]: byte = k4*1040 + q*16 + ki*4
//                      (OOB slots garbage — discarded by the bounds select)
#define MSK 32768u

__global__ __launch_bounds__(256, 3)
void win_attn_kernel(const float* __restrict__ x,
                     const float* __restrict__ mask,
                     const float* __restrict__ proj_b,
                     const char*  __restrict__ ws,
                     float* __restrict__ out) {
  __shared__ __align__(16) char smem[49408];
  const int b    = blockIdx.x;
  const int tid  = threadIdx.x;
  const int w    = tid >> 6;        // wave id == head id
  const int lane = tid & 63;
  const int l16  = lane & 15;
  const int lg   = lane >> 4;

  const unsigned short* qkvP  = (const unsigned short*)(ws + OFF_QKVT);
  const unsigned short* projP = (const unsigned short*)(ws + OFF_PROJT);
  const float* bp  = (const float*)(ws + OFF_BIAST) + w * 4096;  // [k4][q][ki]
  const float* bsc = (const float*)(ws + OFF_BSC);

  // ============ stage x (fp32, 512+XOR) + mask (stride-1040) -> LDS ============
  {
    const float* xb = x + (size_t)b * 6272;
#pragma unroll
    for (int it = 0; it < 8; ++it) {
      int idx = tid + it * 256;                // 2048 chunks of 16B: tok*32+c
      int tok = idx >> 5, c = idx & 31;
      unsigned off = (unsigned)tok * 512u +
                     (((unsigned)c * 16u) ^ (((unsigned)tok & 15u) << 5));
      if (tok < 49) {
        *(float4*)(smem + off) = *(const float4*)(xb + tok * 128 + c * 4);
      } else {
        *(float4*)(smem + off) = make_float4(0.f, 0.f, 0.f, 0.f);
      }
    }
    const float* mb = mask + (size_t)b * 2401;
#pragma unroll
    for (int it = 0; it < 10; ++it) {
      int i = tid + it * 256;
      if (i < 2401) {
        int q = i / 49, key = i - q * 49;
        unsigned off = MSK + (unsigned)(key >> 2) * 1040u +
                       (unsigned)q * 16u + ((unsigned)key & 3u) * 4u;
        *(float*)(smem + off) = mb[i];
      }
    }
  }
  __syncthreads();

  // x fragment from LDS (lane = token l16), pack fp32->bf16 at read (R12 pattern)
  auto xfrag = [&](int tt, int ks) -> bf16x8 {
    int tok = 16 * tt + l16;
    unsigned col = (unsigned)(128 * ks + 32 * lg);
    unsigned off = (unsigned)tok * 512u + (col ^ (((unsigned)tok & 15u) << 5));
    float4 v0 = *(const float4*)(smem + off);
    float4 v1 = *(const float4*)(smem + off + 16);
    union { u32x4 u; bf16x8 h; } pk;
    pk.u.x = pk2(v0.x, v0.y); pk.u.y = pk2(v0.z, v0.w);
    pk.u.z = pk2(v1.x, v1.y); pk.u.w = pk2(v1.z, v1.w);
    return pk.h;
  };

  // coalesced W fragment: k-chunk kc = 4ks+lg, rows n..n+15 consecutive
  auto wfrag = [&](const unsigned short* base, int N, int kc, int n) -> bf16x8 {
    return *(const bf16x8*)(base + ((size_t)kc * N + n) * 8);
  };

  // ============ GEMM1 pass A: Q^T,K^T tiles = mfma(W^T-frag, x-frag) ============
  f32x4 qt_acc[2][4], kt_acc[2][4];
#pragma unroll
  for (int dt = 0; dt < 2; ++dt) {
    f32x4 qb, kb;
#pragma unroll
    for (int i = 0; i < 4; ++i) {
      qb[i] = bsc[32 * w + 16 * dt + 4 * lg + i];
      kb[i] = bsc[128 + 32 * w + 16 * dt + 4 * lg + i];
    }
#pragma unroll
    for (int tt = 0; tt < 4; ++tt) { qt_acc[dt][tt] = qb; kt_acc[dt][tt] = kb; }
  }
#pragma unroll
  for (int ks = 0; ks < 4; ++ks) {
    int kc = 4 * ks + lg;
    bf16x8 xf[4];
#pragma unroll
    for (int tt = 0; tt < 4; ++tt) xf[tt] = xfrag(tt, ks);
#pragma unroll
    for (int dt = 0; dt < 2; ++dt) {
      bf16x8 wq = wfrag(qkvP, 384, kc, 32 * w + 16 * dt + l16);
      bf16x8 wk = wfrag(qkvP, 384, kc, 128 + 32 * w + 16 * dt + l16);
#pragma unroll
      for (int tt = 0; tt < 4; ++tt) {
        qt_acc[dt][tt] = MFMA_K32(wq, xf[tt], qt_acc[dt][tt]);
        kt_acc[dt][tt] = MFMA_K32(wk, xf[tt], kt_acc[dt][tt]);
      }
    }
  }
  bf16x4 qf[4][2], kf[4][2];
#pragma unroll
  for (int tt = 0; tt < 4; ++tt)
#pragma unroll
    for (int dt = 0; dt < 2; ++dt) {
      qf[tt][dt] = pack4(qt_acc[dt][tt][0], qt_acc[dt][tt][1], qt_acc[dt][tt][2], qt_acc[dt][tt][3]);
      kf[tt][dt] = pack4(kt_acc[dt][tt][0], kt_acc[dt][tt][1], kt_acc[dt][tt][2], kt_acc[dt][tt][3]);
    }

  // ============ GEMM1 pass B: V tiles = mfma(x-frag, Wv^T-frag) ============
  f32x4 v_acc[4][2];
  {
    float vb0 = bsc[256 + 32 * w + l16];
    float vb1 = bsc[256 + 32 * w + 16 + l16];
#pragma unroll
    for (int tt = 0; tt < 4; ++tt) {
      v_acc[tt][0] = (f32x4){vb0, vb0, vb0, vb0};
      v_acc[tt][1] = (f32x4){vb1, vb1, vb1, vb1};
    }
  }
#pragma unroll
  for (int ks = 0; ks < 4; ++ks) {
    int kc = 4 * ks + lg;
    bf16x8 xf[4];
#pragma unroll
    for (int tt = 0; tt < 4; ++tt) xf[tt] = xfrag(tt, ks);   // LDS re-read, cheap
#pragma unroll
    for (int dt = 0; dt < 2; ++dt) {
      bf16x8 wv = wfrag(qkvP, 384, kc, 256 + 32 * w + 16 * dt + l16);
#pragma unroll
      for (int tt = 0; tt < 4; ++tt) v_acc[tt][dt] = MFMA_K32(xf[tt], wv, v_acc[tt][dt]);
    }
  }
  bf16x4 vf[2][4];
#pragma unroll
  for (int dt = 0; dt < 2; ++dt)
#pragma unroll
    for (int tt = 0; tt < 4; ++tt)
      vf[dt][tt] = pack4(v_acc[tt][dt][0], v_acc[tt][dt][1], v_acc[tt][dt][2], v_acc[tt][dt][3]);

  __syncthreads();   // all waves done reading xs; first 16KB becomes `mid`

  // ============ QK^T (K=16): S^T[key][q] tiles, lane = q, regs = key ============
  f32x4 s_acc[4][4];  // [kt][qt]
#pragma unroll
  for (int kt = 0; kt < 4; ++kt)
#pragma unroll
    for (int qt = 0; qt < 4; ++qt) s_acc[kt][qt] = (f32x4){0.f, 0.f, 0.f, 0.f};
#pragma unroll
  for (int kt = 0; kt < 4; ++kt)
#pragma unroll
    for (int qt = 0; qt < 4; ++qt) {
      s_acc[kt][qt] = MFMA_K16(kf[kt][0], qf[qt][0], s_acc[kt][qt]);
      s_acc[kt][qt] = MFMA_K16(kf[kt][1], qf[qt][1], s_acc[kt][qt]);
    }

  // ====== bias (float4, coalesced) + mask (LDS, ~2-way) + no-max softmax ======
  float rs_[4];
#pragma unroll
  for (int qt = 0; qt < 4; ++qt) {
    int q = 16 * qt + l16;
    bool qok = q < 49;
    float sum = 0.f;
#pragma unroll
    for (int kt = 0; kt < 4; ++kt) {
      int k4 = 4 * kt + lg;
      float4 bv = *(const float4*)(bp + k4 * 256 + q * 4);
      float4 mk = *(const float4*)(smem + MSK + (unsigned)k4 * 1040u + (unsigned)q * 16u);
      float ba[4] = {bv.x + mk.x, bv.y + mk.y, bv.z + mk.z, bv.w + mk.w};
#pragma unroll
      for (int i = 0; i < 4; ++i) {
        int key = 16 * kt + 4 * lg + i;
        float v = s_acc[kt][qt][i];
        v = (qok && key < 49) ? (v + ba[i]) : -30000.0f;
        float e = __expf(v - 8.0f);
        s_acc[kt][qt][i] = e;
        sum += e;
      }
    }
    sum += __shfl_xor(sum, 16);
    sum += __shfl_xor(sum, 32);
    rs_[qt] = 1.0f / (sum + 1e-30f);   // padded rows: sum==0 -> rs finite
  }

  // ============ P frags in-register; PV (K=16): O^T[d][q], lane = q ============
  bf16x4 pf[4][4];  // [qt][kt]
#pragma unroll
  for (int qt = 0; qt < 4; ++qt)
#pragma unroll
    for (int kt = 0; kt < 4; ++kt)
      pf[qt][kt] = pack4(s_acc[kt][qt][0], s_acc[kt][qt][1], s_acc[kt][qt][2], s_acc[kt][qt][3]);

  f32x4 o_acc[2][4];  // [dt][qt]: lane = q, regs = d = 4lg+i
#pragma unroll
  for (int dt = 0; dt < 2; ++dt)
#pragma unroll
    for (int qt = 0; qt < 4; ++qt) o_acc[dt][qt] = (f32x4){0.f, 0.f, 0.f, 0.f};
#pragma unroll
  for (int kt = 0; kt < 4; ++kt)
#pragma unroll
    for (int dt = 0; dt < 2; ++dt)
#pragma unroll
      for (int qt = 0; qt < 4; ++qt)
        o_acc[dt][qt] = MFMA_K16(vf[dt][kt], pf[qt][kt], o_acc[dt][qt]);

  // ============ normalize + write mid[q][32w+16dt+4lg..+3] (uint2) ============
#pragma unroll
  for (int qt = 0; qt < 4; ++qt) {
    int q = 16 * qt + l16;
    float r = rs_[qt];
    unsigned rowb = (unsigned)q * 256u, sw = ((unsigned)q & 15u) << 4;
#pragma unroll
    for (int dt = 0; dt < 2; ++dt) {
      unsigned u0 = pk2(o_acc[dt][qt][0] * r, o_acc[dt][qt][1] * r);
      unsigned u1 = pk2(o_acc[dt][qt][2] * r, o_acc[dt][qt][3] * r);
      unsigned L = (unsigned)(64 * w + 32 * dt + 8 * lg);
      *(uint2*)(smem + rowb + (L ^ sw)) = make_uint2(u0, u1);
    }
  }
  __syncthreads();

  // ============ GEMM2 (K=32): out = mid @ projW + b; wave w: cols 32w..32w+31 ============
  f32x4 c2[2][4];
#pragma unroll
  for (int nt = 0; nt < 2; ++nt) {
    float pbv = proj_b[32 * w + 16 * nt + l16];
#pragma unroll
    for (int mt = 0; mt < 4; ++mt) c2[nt][mt] = (f32x4){pbv, pbv, pbv, pbv};
  }
#pragma unroll
  for (int ks = 0; ks < 4; ++ks) {
    int kc = 4 * ks + lg;
    bf16x8 a2[4];
#pragma unroll
    for (int mt = 0; mt < 4; ++mt) {
      int tok = 16 * mt + l16;
      unsigned byte = (unsigned)tok * 256u +
                      (((unsigned)(64 * ks + 16 * lg)) ^ (((unsigned)tok & 15u) << 4));
      a2[mt] = *(const bf16x8*)(smem + byte);
    }
#pragma unroll
    for (int nt = 0; nt < 2; ++nt) {
      bf16x8 b2 = wfrag(projP, 128, kc, 32 * w + 16 * nt + l16);
#pragma unroll
      for (int mt = 0; mt < 4; ++mt) c2[nt][mt] = MFMA_K32(a2[mt], b2, c2[nt][mt]);
    }
  }
  float* ob = out + (size_t)b * 6272;
#pragma unroll
  for (int mt = 0; mt < 4; ++mt)
#pragma unroll
    for (int nt = 0; nt < 2; ++nt)
#pragma unroll
      for (int i = 0; i < 4; ++i) {
        int r = 16 * mt + 4 * lg + i;
        if (r < 49) ob[r * 128 + 32 * w + 16 * nt + l16] = c2[nt][mt][i];
      }
}

extern "C" void kernel_launch(void* const* d_in, const int* in_sizes, int n_in,
                              void* d_out, int out_size, void* d_ws, size_t ws_size,
                              hipStream_t stream) {
  const float* x          = (const float*)d_in[0];
  const float* mask       = (const float*)d_in[1];
  const float* qkv_w      = (const float*)d_in[2];
  const float* qkv_b      = (const float*)d_in[3];
  const float* proj_w     = (const float*)d_in[4];
  const float* proj_b     = (const float*)d_in[5];
  const float* bias_table = (const float*)d_in[6];
  const int*   rel_index  = (const int*)d_in[7];
  char* ws = (char*)d_ws;

  prep_kernel<<<296, 256, 0, stream>>>(qkv_w, qkv_b, proj_w, bias_table, rel_index, ws);
  win_attn_kernel<<<4096, 256, 0, stream>>>(x, mask, proj_b, ws, (float*)d_out);
}